// Round 13
// baseline (72.304 us; speedup 1.0000x reference)
//
#include <hip/hip_runtime.h>
#include <math.h>

#define D 256          // feature dim (fixed by reference)
#define NREL 16        // relation count
#define CHUNK 6250     // nodes per dst-chunk (2 x f32 LDS arrays = 50 KB)
#define BPC 32         // blocks per chunk (edge-slice parallelism)
#define XW 129         // x half-tile row stride (b32 reads: bank (nl+d)%32 -> 2-way free)
#define WBASE (64 * XW)  // W region starts after x tile (8256 floats, 16B-aligned)

typedef float f4v __attribute__((ext_vector_type(4)));

// ---------------------------------------------------------------------------
// Kernel A v10: y[n][r] = dot(x[n], W[r]) r<16, xr[n] = dot(x[n], root).
// KEY CHANGE vs v4/v8: W and root are staged into LDS once per block and read
// with wave-uniform ds_read_b128 (broadcast, conflict-free). The inner loop
// now has NO SMEM loads -> pure-DS lgkmcnt domain (in-order) -> the compiler
// can use counted lgkmcnt(N) waits instead of the lgkmcnt(0) full drains that
// mixed s_load/ds_read code requires (SMEM retires out of order). This was
// the latency serializer common to all previous A variants.
// Geometry: v4's two 128-d halves, x tile [64][129] scalar-b32 (2-way banks,
// free), rg = t>>6 owns W rows {4rg..4rg+3}; rg 3 also accumulates root
// (stored as W row 16). LDS total 50.4 KB -> 3 blocks/CU.
// ---------------------------------------------------------------------------
__global__ __launch_bounds__(256) void rgcn_y_kernel(
    const float* __restrict__ x, const float* __restrict__ w,
    const float* __restrict__ root, float* __restrict__ y,
    float* __restrict__ xr, int n)
{
    __shared__ float lds[WBASE + 17 * 256];   // 50432 B
    const int t = threadIdx.x;
    const int nl = t & 63;
    const int rg = __builtin_amdgcn_readfirstlane(t >> 6);  // wave-uniform
    const int base = blockIdx.x * 64;
    const int node = base + nl;

    // ---- stage W (rows 0..15) + root (row 16) into LDS, float4-coalesced ----
    #pragma unroll
    for (int k = 0; k < 4; ++k) {
        int slot = k * 256 + t;               // 1024 float4 slots = 16x256
        float4 v = *reinterpret_cast<const float4*>(w + (size_t)slot * 4);
        *reinterpret_cast<float4*>(&lds[WBASE + slot * 4]) = v;
    }
    if (t < 64) {
        float4 v = *reinterpret_cast<const float4*>(root + (size_t)t * 4);
        *reinterpret_cast<float4*>(&lds[WBASE + 16 * 256 + t * 4]) = v;
    }
    // (visibility covered by the first x-half barrier below)

    const int wr  = rg * 4;                   // this wave's W row group
    const int w4r = (rg == 3) ? 16 : wr;      // root row for rg3, dummy else

    float a0 = 0.f, a1 = 0.f, a2 = 0.f, a3 = 0.f, aR = 0.f;

    #pragma unroll
    for (int h = 0; h < 2; ++h) {   // two 128-d halves
        // ---- stage 64 nodes x 128 d: 8 independent float4 loads/thread ----
        #pragma unroll
        for (int k = 0; k < 8; ++k) {
            int flat = k * 256 + t;       // float4 slot 0..2047
            int snl  = flat >> 5;         // staged node local 0..63
            int c16  = flat & 31;         // float4 idx within 128-d half
            int gn   = base + snl;
            float4 v = make_float4(0.f, 0.f, 0.f, 0.f);
            if (gn < n)
                v = *reinterpret_cast<const float4*>(
                        x + (size_t)gn * D + h * 128 + c16 * 4);
            int a = snl * XW + c16 * 4;   // scalar stores (rows not 16B-aligned)
            lds[a + 0] = v.x; lds[a + 1] = v.y;
            lds[a + 2] = v.z; lds[a + 3] = v.w;
        }
        __syncthreads();

        const int ho = h * 128;           // column offset within W rows
        #pragma unroll 8
        for (int dq = 0; dq < 32; ++dq) {
            // wave-uniform W reads: ds_read_b128 broadcast, conflict-free
            float4 w0v = *reinterpret_cast<const float4*>(
                             &lds[WBASE + (wr + 0) * 256 + ho + dq * 4]);
            float4 w1v = *reinterpret_cast<const float4*>(
                             &lds[WBASE + (wr + 1) * 256 + ho + dq * 4]);
            float4 w2v = *reinterpret_cast<const float4*>(
                             &lds[WBASE + (wr + 2) * 256 + ho + dq * 4]);
            float4 w3v = *reinterpret_cast<const float4*>(
                             &lds[WBASE + (wr + 3) * 256 + ho + dq * 4]);
            float4 w4v = *reinterpret_cast<const float4*>(
                             &lds[WBASE + w4r * 256 + ho + dq * 4]);
            // per-node x reads: scalar b32, bank (nl+d)%32 -> 2-way (free)
            float x0 = lds[nl * XW + dq * 4 + 0];
            float x1 = lds[nl * XW + dq * 4 + 1];
            float x2 = lds[nl * XW + dq * 4 + 2];
            float x3 = lds[nl * XW + dq * 4 + 3];

            a0 = fmaf(x0, w0v.x, a0); a0 = fmaf(x1, w0v.y, a0);
            a0 = fmaf(x2, w0v.z, a0); a0 = fmaf(x3, w0v.w, a0);
            a1 = fmaf(x0, w1v.x, a1); a1 = fmaf(x1, w1v.y, a1);
            a1 = fmaf(x2, w1v.z, a1); a1 = fmaf(x3, w1v.w, a1);
            a2 = fmaf(x0, w2v.x, a2); a2 = fmaf(x1, w2v.y, a2);
            a2 = fmaf(x2, w2v.z, a2); a2 = fmaf(x3, w2v.w, a2);
            a3 = fmaf(x0, w3v.x, a3); a3 = fmaf(x1, w3v.y, a3);
            a3 = fmaf(x2, w3v.z, a3); a3 = fmaf(x3, w3v.w, a3);
            aR = fmaf(x0, w4v.x, aR); aR = fmaf(x1, w4v.y, aR);
            aR = fmaf(x2, w4v.z, aR); aR = fmaf(x3, w4v.w, aR);
        }
        if (h == 0) __syncthreads();   // tile reuse barrier
    }

    if (node < n) {
        float4 o; o.x = a0; o.y = a1; o.z = a2; o.w = a3;
        *reinterpret_cast<float4*>(y + (size_t)node * NREL + rg * 4) = o;
        if (rg == 3) xr[node] = aR;
    }
}

// ---------------------------------------------------------------------------
// Kernel B: chunked edge scan, LDS accumulation, zero global atomics.
// Unconditional int4 loads of dst/src/et (3 independent vector loads per
// 4-edge group -> deep memory-level parallelism).
// ---------------------------------------------------------------------------
__global__ __launch_bounds__(1024) void rgcn_edge_scan_kernel(
    const int* __restrict__ src, const int* __restrict__ dst,
    const int* __restrict__ et, const float* __restrict__ y,
    float2* __restrict__ partial, int e, int sl)
{
    __shared__ float lsum[CHUNK];
    __shared__ float lcnt[CHUNK];
    const int t = threadIdx.x;
    const int c = blockIdx.x / BPC;
    const int b = blockIdx.x % BPC;
    const int base = c * CHUNK;

    for (int j = t; j < CHUNK; j += 1024) { lsum[j] = 0.f; lcnt[j] = 0.f; }
    __syncthreads();

    const int slice0 = b * sl;
    const int rem = e - slice0;
    if (rem > 0) {
        const int gmax = (min(sl, rem) + 3) >> 2;   // int4 groups in slice
        for (int g = t; g < gmax; g += 1024) {
            int idx = slice0 + g * 4;
            if (idx + 3 < e) {
                int4 d4 = *reinterpret_cast<const int4*>(dst + idx);
                int4 s4 = *reinterpret_cast<const int4*>(src + idx);
                int4 r4 = *reinterpret_cast<const int4*>(et + idx);
                int loc0 = d4.x - base, loc1 = d4.y - base;
                int loc2 = d4.z - base, loc3 = d4.w - base;
                if ((unsigned)loc0 < (unsigned)CHUNK) {
                    atomicAdd(&lsum[loc0], y[(size_t)s4.x * NREL + r4.x]);
                    atomicAdd(&lcnt[loc0], 1.0f);
                }
                if ((unsigned)loc1 < (unsigned)CHUNK) {
                    atomicAdd(&lsum[loc1], y[(size_t)s4.y * NREL + r4.y]);
                    atomicAdd(&lcnt[loc1], 1.0f);
                }
                if ((unsigned)loc2 < (unsigned)CHUNK) {
                    atomicAdd(&lsum[loc2], y[(size_t)s4.z * NREL + r4.z]);
                    atomicAdd(&lcnt[loc2], 1.0f);
                }
                if ((unsigned)loc3 < (unsigned)CHUNK) {
                    atomicAdd(&lsum[loc3], y[(size_t)s4.w * NREL + r4.w]);
                    atomicAdd(&lcnt[loc3], 1.0f);
                }
            } else {
                for (int k = idx; k < e && k < idx + 4; ++k) {
                    int loc = dst[k] - base;
                    if ((unsigned)loc < (unsigned)CHUNK) {
                        atomicAdd(&lsum[loc], y[(size_t)src[k] * NREL + et[k]]);
                        atomicAdd(&lcnt[loc], 1.0f);
                    }
                }
            }
        }
    }
    __syncthreads();

    float2* p = partial + ((size_t)(c * BPC + b)) * CHUNK;
    for (int j = t; j < CHUNK; j += 1024)
        p[j] = make_float2(lsum[j], lcnt[j]);
}

// ---------------------------------------------------------------------------
// Kernel C (fused finish), 32 nodes/block:
//   phase 1 (ALL threads): thread t reduces 4 partials of node t&31
//                          (b-group t>>5), LDS-atomic combine;
//                          then 32 threads do tanh -> sc[] + out_score.
//   phase 2 (all):  x_out = x * score, nontemporal float4 stores.
// ---------------------------------------------------------------------------
__global__ __launch_bounds__(256) void rgcn_finish_kernel(
    const float2* __restrict__ partial, const float* __restrict__ xr,
    const float* __restrict__ bias, const float* __restrict__ x,
    float* __restrict__ out_x, float* __restrict__ out_score, int n)
{
    __shared__ float ssum[32], scnt[32], sc[32];
    const int t = threadIdx.x;
    const int base = blockIdx.x * 32;

    if (t < 32) { ssum[t] = 0.f; scnt[t] = 0.f; }
    __syncthreads();

    {
        int nl = t & 31;
        int bg = t >> 5;                 // 0..7, covers BPC=32 in 4s
        int node = base + nl;
        float s = 0.f, cN = 0.f;
        if (node < n) {
            int c = node / CHUNK;
            int j = node - c * CHUNK;
            const float2* p = partial + (size_t)c * BPC * CHUNK + j;
            #pragma unroll
            for (int b = 0; b < 4; ++b) {
                float2 v = p[(size_t)(bg * 4 + b) * CHUNK];
                s += v.x; cN += v.y;
            }
        }
        atomicAdd(&ssum[nl], s);
        atomicAdd(&scnt[nl], cN);
    }
    __syncthreads();

    if (t < 32) {
        int node = base + t;
        if (node < n) {
            float m = ssum[t] / fmaxf(scnt[t], 1.0f);
            float v = tanhf(m + xr[node] + bias[0]);
            sc[t] = v;
            out_score[node] = v;
        }
    }
    __syncthreads();

    #pragma unroll
    for (int k = 0; k < 8; ++k) {
        int nl = k * 4 + (t >> 6);       // node local 0..31
        int f4 = t & 63;                 // float4 index in row
        int node = base + nl;
        if (node < n) {
            float s = sc[nl];
            float4 v = *reinterpret_cast<const float4*>(
                           x + (size_t)node * D + f4 * 4);
            v.x *= s; v.y *= s; v.z *= s; v.w *= s;
            f4v vo = {v.x, v.y, v.z, v.w};
            __builtin_nontemporal_store(
                vo, (f4v*)(out_x + (size_t)node * D + f4 * 4));
        }
    }
}

// --------------------- fallback path (scratch in out tail) -----------------
__global__ __launch_bounds__(256) void rgcn_reduce_score_kernel(
    const float2* __restrict__ partial, const float* __restrict__ xr,
    const float* __restrict__ bias, float* __restrict__ score, int n)
{
    int i = blockIdx.x * 256 + threadIdx.x;
    if (i < n) {
        int c = i / CHUNK;
        int j = i - c * CHUNK;
        const float2* p = partial + (size_t)c * BPC * CHUNK + j;
        float s = 0.f, cN = 0.f;
        #pragma unroll 8
        for (int b = 0; b < BPC; ++b) {
            float2 v = p[(size_t)b * CHUNK];
            s += v.x; cN += v.y;
        }
        float m = s / fmaxf(cN, 1.0f);
        score[i] = tanhf(m + xr[i] + bias[0]);
    }
}

__global__ __launch_bounds__(256) void rgcn_scale_kernel(
    const float* __restrict__ x, const float* __restrict__ score,
    float* __restrict__ xo, int n)
{
    int gid = blockIdx.x * 256 + threadIdx.x;
    int node = gid >> 6;
    int f4 = gid & 63;
    if (node < n) {
        float s = score[node];
        float4 v = *reinterpret_cast<const float4*>(
                       x + (size_t)node * D + f4 * 4);
        v.x *= s; v.y *= s; v.z *= s; v.w *= s;
        *reinterpret_cast<float4*>(xo + (size_t)node * D + f4 * 4) = v;
    }
}

extern "C" void kernel_launch(void* const* d_in, const int* in_sizes, int n_in,
                              void* d_out, int out_size, void* d_ws, size_t ws_size,
                              hipStream_t stream)
{
    const float* x    = (const float*)d_in[0];
    const int*   ei   = (const int*)d_in[1];   // (2, E): src then dst
    const int*   et   = (const int*)d_in[2];
    const float* w    = (const float*)d_in[3]; // (R, D, 1) -> flat r*D+d
    const float* root = (const float*)d_in[4]; // (D, 1)    -> flat d
    const float* bias = (const float*)d_in[5];

    const int n = in_sizes[0] / D;   // 50000
    const int e = in_sizes[2];       // 800000

    float* out       = (float*)d_out;
    float* out_x     = out;                       // n*D floats
    float* out_score = out + (size_t)n * D;       // n floats

    const int C = (n + CHUNK - 1) / CHUNK;        // 8 for n=50000
    const int sl = ((((e + BPC - 1) / BPC) + 3) & ~3);  // slice len, mult of 4

    // Scratch: partials (C*BPC*CHUNK float2) | y (16n) | xr (n)
    const size_t part_f = (size_t)C * BPC * CHUNK * 2;   // floats
    const size_t need_f = part_f + (size_t)n * (NREL + 1);
    const bool use_ws = (ws_size >= need_f * sizeof(float));

    float* sb;
    if (use_ws)
        sb = (float*)d_ws;
    else {
        size_t ts = (((size_t)n * D - need_f) & ~(size_t)1);  // 8B-align
        sb = out_x + ts;
    }
    float2* partial = (float2*)sb;
    float*  y  = sb + part_f;
    float*  xr = y + (size_t)n * NREL;

    rgcn_y_kernel<<<dim3((n + 63) / 64), dim3(256), 0, stream>>>(
        x, w, root, y, xr, n);

    rgcn_edge_scan_kernel<<<dim3(C * BPC), dim3(1024), 0, stream>>>(
        ei, ei + e, et, y, partial, e, sl);

    if (use_ws) {
        rgcn_finish_kernel<<<dim3((n + 31) / 32), dim3(256), 0, stream>>>(
            partial, xr, bias, x, out_x, out_score, n);
    } else {
        rgcn_reduce_score_kernel<<<dim3((n + 255) / 256), dim3(256), 0, stream>>>(
            partial, xr, bias, out_score, n);
        rgcn_scale_kernel<<<dim3((int)(((size_t)n * 64 + 255) / 256)), dim3(256), 0, stream>>>(
            x, out_score, out_x, n);
    }
}

// Round 15
// 61.539 us; speedup vs baseline: 1.1749x; 1.1749x over previous
//
#include <hip/hip_runtime.h>
#include <math.h>

#define D 256          // feature dim (fixed by reference)
#define NREL 16        // relation count
#define CHUNK 6250     // nodes per dst-chunk (2 x f32 LDS arrays = 50 KB)
#define BPC 32         // blocks per chunk (edge-slice parallelism)

typedef float f4v __attribute__((ext_vector_type(4)));
typedef __attribute__((ext_vector_type(8))) short bf16x8;
typedef __attribute__((ext_vector_type(4))) float f32x4;

// round-to-nearest-even f32 -> bf16
__device__ __forceinline__ short f2bf(float f) {
    union { float f; unsigned u; } v; v.f = f;
    unsigned r = v.u + 0x7FFFu + ((v.u >> 16) & 1u);
    return (short)(r >> 16);
}

// ---------------------------------------------------------------------------
// Kernel A v12 (MFMA): y[n][r] = dot(x[n], W[r]) r<16, xr[n] = dot(x[n],root).
// One wave = 16 nodes. A-frag: lane l holds x[base+(l&15)][(l>>4)*8+j+32kk]
// (8 consecutive k per lane -> two float4 loads, cvt to bf16). B-frag: lane l
// holds W[l&15][same k slice] (B col = rel = l&15). Root handled by a second
// MFMA with B-col 0 = root, cols 1..15 = 0. K=256 -> 8 MFMA steps per output.
// D layout (HW-verified m89): col = l&15 (rel), row = (l>>4)*4 + reg (node).
// A/B share the same (lane,j)->k map, so any k-permutation cancels in the dot.
// No LDS, no barriers, no shuffles; reduction runs in the matrix pipe.
// ---------------------------------------------------------------------------
__global__ __launch_bounds__(256) void rgcn_y_kernel(
    const float* __restrict__ x, const float* __restrict__ w,
    const float* __restrict__ root, float* __restrict__ y,
    float* __restrict__ xr, int n)
{
    const int t    = threadIdx.x;
    const int l    = t & 63;
    const int wv   = t >> 6;
    const int base = blockIdx.x * 64 + wv * 16;
    const int arow = l & 15;      // A row = node-in-tile; also B/D col = rel
    const int kgrp = l >> 4;      // 0..3

    const bool okA = (base + arow) < n;
    const float* xp = x + (size_t)(base + arow) * D + kgrp * 8;
    const float* wp = w + (size_t)arow * D + kgrp * 8;
    const float* rp = root + kgrp * 8;

    f32x4 acc  = {0.f, 0.f, 0.f, 0.f};
    f32x4 accR = {0.f, 0.f, 0.f, 0.f};

    #pragma unroll
    for (int kk = 0; kk < 8; ++kk) {
        float4 xa = make_float4(0.f, 0.f, 0.f, 0.f), xb = xa;
        if (okA) {
            xa = *reinterpret_cast<const float4*>(xp + kk * 32);
            xb = *reinterpret_cast<const float4*>(xp + kk * 32 + 4);
        }
        bf16x8 af;
        af[0] = f2bf(xa.x); af[1] = f2bf(xa.y);
        af[2] = f2bf(xa.z); af[3] = f2bf(xa.w);
        af[4] = f2bf(xb.x); af[5] = f2bf(xb.y);
        af[6] = f2bf(xb.z); af[7] = f2bf(xb.w);

        float4 wa = *reinterpret_cast<const float4*>(wp + kk * 32);
        float4 wb = *reinterpret_cast<const float4*>(wp + kk * 32 + 4);
        bf16x8 bfr;
        bfr[0] = f2bf(wa.x); bfr[1] = f2bf(wa.y);
        bfr[2] = f2bf(wa.z); bfr[3] = f2bf(wa.w);
        bfr[4] = f2bf(wb.x); bfr[5] = f2bf(wb.y);
        bfr[6] = f2bf(wb.z); bfr[7] = f2bf(wb.w);

        acc = __builtin_amdgcn_mfma_f32_16x16x32_bf16(af, bfr, acc, 0, 0, 0);

        bf16x8 rf = {0, 0, 0, 0, 0, 0, 0, 0};
        if (arow == 0) {
            float4 ra = *reinterpret_cast<const float4*>(rp + kk * 32);
            float4 rb = *reinterpret_cast<const float4*>(rp + kk * 32 + 4);
            rf[0] = f2bf(ra.x); rf[1] = f2bf(ra.y);
            rf[2] = f2bf(ra.z); rf[3] = f2bf(ra.w);
            rf[4] = f2bf(rb.x); rf[5] = f2bf(rb.y);
            rf[6] = f2bf(rb.z); rf[7] = f2bf(rb.w);
        }
        accR = __builtin_amdgcn_mfma_f32_16x16x32_bf16(af, rf, accR, 0, 0, 0);
    }

    #pragma unroll
    for (int reg = 0; reg < 4; ++reg) {
        int node = base + kgrp * 4 + reg;
        if (node < n) {
            y[(size_t)node * NREL + arow] = acc[reg];
            if (arow == 0) xr[node] = accR[reg];
        }
    }
}

// ---------------------------------------------------------------------------
// Kernel B: chunked edge scan, LDS accumulation, zero global atomics.
// [identical to R8]
// ---------------------------------------------------------------------------
__global__ __launch_bounds__(1024) void rgcn_edge_scan_kernel(
    const int* __restrict__ src, const int* __restrict__ dst,
    const int* __restrict__ et, const float* __restrict__ y,
    float2* __restrict__ partial, int e, int sl)
{
    __shared__ float lsum[CHUNK];
    __shared__ float lcnt[CHUNK];
    const int t = threadIdx.x;
    const int c = blockIdx.x / BPC;
    const int b = blockIdx.x % BPC;
    const int base = c * CHUNK;

    for (int j = t; j < CHUNK; j += 1024) { lsum[j] = 0.f; lcnt[j] = 0.f; }
    __syncthreads();

    const int slice0 = b * sl;
    const int rem = e - slice0;
    if (rem > 0) {
        const int gmax = (min(sl, rem) + 3) >> 2;   // int4 groups in slice
        for (int g = t; g < gmax; g += 1024) {
            int idx = slice0 + g * 4;
            if (idx + 3 < e) {
                int4 d4 = *reinterpret_cast<const int4*>(dst + idx);
                int4 s4 = *reinterpret_cast<const int4*>(src + idx);
                int4 r4 = *reinterpret_cast<const int4*>(et + idx);
                int loc0 = d4.x - base, loc1 = d4.y - base;
                int loc2 = d4.z - base, loc3 = d4.w - base;
                if ((unsigned)loc0 < (unsigned)CHUNK) {
                    atomicAdd(&lsum[loc0], y[(size_t)s4.x * NREL + r4.x]);
                    atomicAdd(&lcnt[loc0], 1.0f);
                }
                if ((unsigned)loc1 < (unsigned)CHUNK) {
                    atomicAdd(&lsum[loc1], y[(size_t)s4.y * NREL + r4.y]);
                    atomicAdd(&lcnt[loc1], 1.0f);
                }
                if ((unsigned)loc2 < (unsigned)CHUNK) {
                    atomicAdd(&lsum[loc2], y[(size_t)s4.z * NREL + r4.z]);
                    atomicAdd(&lcnt[loc2], 1.0f);
                }
                if ((unsigned)loc3 < (unsigned)CHUNK) {
                    atomicAdd(&lsum[loc3], y[(size_t)s4.w * NREL + r4.w]);
                    atomicAdd(&lcnt[loc3], 1.0f);
                }
            } else {
                for (int k = idx; k < e && k < idx + 4; ++k) {
                    int loc = dst[k] - base;
                    if ((unsigned)loc < (unsigned)CHUNK) {
                        atomicAdd(&lsum[loc], y[(size_t)src[k] * NREL + et[k]]);
                        atomicAdd(&lcnt[loc], 1.0f);
                    }
                }
            }
        }
    }
    __syncthreads();

    float2* p = partial + ((size_t)(c * BPC + b)) * CHUNK;
    for (int j = t; j < CHUNK; j += 1024)
        p[j] = make_float2(lsum[j], lcnt[j]);
}

// ---------------------------------------------------------------------------
// Kernel C (fused finish), 32 nodes/block.  [identical to R8]
// ---------------------------------------------------------------------------
__global__ __launch_bounds__(256) void rgcn_finish_kernel(
    const float2* __restrict__ partial, const float* __restrict__ xr,
    const float* __restrict__ bias, const float* __restrict__ x,
    float* __restrict__ out_x, float* __restrict__ out_score, int n)
{
    __shared__ float ssum[32], scnt[32], sc[32];
    const int t = threadIdx.x;
    const int base = blockIdx.x * 32;

    if (t < 32) { ssum[t] = 0.f; scnt[t] = 0.f; }
    __syncthreads();

    {
        int nl = t & 31;
        int bg = t >> 5;                 // 0..7, covers BPC=32 in 4s
        int node = base + nl;
        float s = 0.f, cN = 0.f;
        if (node < n) {
            int c = node / CHUNK;
            int j = node - c * CHUNK;
            const float2* p = partial + (size_t)c * BPC * CHUNK + j;
            #pragma unroll
            for (int b = 0; b < 4; ++b) {
                float2 v = p[(size_t)(bg * 4 + b) * CHUNK];
                s += v.x; cN += v.y;
            }
        }
        atomicAdd(&ssum[nl], s);
        atomicAdd(&scnt[nl], cN);
    }
    __syncthreads();

    if (t < 32) {
        int node = base + t;
        if (node < n) {
            float m = ssum[t] / fmaxf(scnt[t], 1.0f);
            float v = tanhf(m + xr[node] + bias[0]);
            sc[t] = v;
            out_score[node] = v;
        }
    }
    __syncthreads();

    #pragma unroll
    for (int k = 0; k < 8; ++k) {
        int nl = k * 4 + (t >> 6);       // node local 0..31
        int f4 = t & 63;                 // float4 index in row
        int node = base + nl;
        if (node < n) {
            float s = sc[nl];
            float4 v = *reinterpret_cast<const float4*>(
                           x + (size_t)node * D + f4 * 4);
            v.x *= s; v.y *= s; v.z *= s; v.w *= s;
            f4v vo = {v.x, v.y, v.z, v.w};
            __builtin_nontemporal_store(
                vo, (f4v*)(out_x + (size_t)node * D + f4 * 4));
        }
    }
}

// --------------------- fallback path (scratch in out tail) -----------------
__global__ __launch_bounds__(256) void rgcn_reduce_score_kernel(
    const float2* __restrict__ partial, const float* __restrict__ xr,
    const float* __restrict__ bias, float* __restrict__ score, int n)
{
    int i = blockIdx.x * 256 + threadIdx.x;
    if (i < n) {
        int c = i / CHUNK;
        int j = i - c * CHUNK;
        const float2* p = partial + (size_t)c * BPC * CHUNK + j;
        float s = 0.f, cN = 0.f;
        #pragma unroll 8
        for (int b = 0; b < BPC; ++b) {
            float2 v = p[(size_t)b * CHUNK];
            s += v.x; cN += v.y;
        }
        float m = s / fmaxf(cN, 1.0f);
        score[i] = tanhf(m + xr[i] + bias[0]);
    }
}

__global__ __launch_bounds__(256) void rgcn_scale_kernel(
    const float* __restrict__ x, const float* __restrict__ score,
    float* __restrict__ xo, int n)
{
    int gid = blockIdx.x * 256 + threadIdx.x;
    int node = gid >> 6;
    int f4 = gid & 63;
    if (node < n) {
        float s = score[node];
        float4 v = *reinterpret_cast<const float4*>(
                       x + (size_t)node * D + f4 * 4);
        v.x *= s; v.y *= s; v.z *= s; v.w *= s;
        *reinterpret_cast<float4*>(xo + (size_t)node * D + f4 * 4) = v;
    }
}

extern "C" void kernel_launch(void* const* d_in, const int* in_sizes, int n_in,
                              void* d_out, int out_size, void* d_ws, size_t ws_size,
                              hipStream_t stream)
{
    const float* x    = (const float*)d_in[0];
    const int*   ei   = (const int*)d_in[1];   // (2, E): src then dst
    const int*   et   = (const int*)d_in[2];
    const float* w    = (const float*)d_in[3]; // (R, D, 1) -> flat r*D+d
    const float* root = (const float*)d_in[4]; // (D, 1)    -> flat d
    const float* bias = (const float*)d_in[5];

    const int n = in_sizes[0] / D;   // 50000
    const int e = in_sizes[2];       // 800000

    float* out       = (float*)d_out;
    float* out_x     = out;                       // n*D floats
    float* out_score = out + (size_t)n * D;       // n floats

    const int C = (n + CHUNK - 1) / CHUNK;        // 8 for n=50000
    const int sl = ((((e + BPC - 1) / BPC) + 3) & ~3);  // slice len, mult of 4

    // Scratch: partials (C*BPC*CHUNK float2) | y (16n) | xr (n)
    const size_t part_f = (size_t)C * BPC * CHUNK * 2;   // floats
    const size_t need_f = part_f + (size_t)n * (NREL + 1);
    const bool use_ws = (ws_size >= need_f * sizeof(float));

    float* sb;
    if (use_ws)
        sb = (float*)d_ws;
    else {
        size_t ts = (((size_t)n * D - need_f) & ~(size_t)1);  // 8B-align
        sb = out_x + ts;
    }
    float2* partial = (float2*)sb;
    float*  y  = sb + part_f;
    float*  xr = y + (size_t)n * NREL;

    rgcn_y_kernel<<<dim3((n + 63) / 64), dim3(256), 0, stream>>>(
        x, w, root, y, xr, n);

    rgcn_edge_scan_kernel<<<dim3(C * BPC), dim3(1024), 0, stream>>>(
        ei, ei + e, et, y, partial, e, sl);

    if (use_ws) {
        rgcn_finish_kernel<<<dim3((n + 31) / 32), dim3(256), 0, stream>>>(
            partial, xr, bias, x, out_x, out_score, n);
    } else {
        rgcn_reduce_score_kernel<<<dim3((n + 255) / 256), dim3(256), 0, stream>>>(
            partial, xr, bias, out_score, n);
        rgcn_scale_kernel<<<dim3((int)(((size_t)n * 64 + 255) / 256)), dim3(256), 0, stream>>>(
            x, out_score, out_x, n);
    }
}